// Round 5
// baseline (495.042 us; speedup 1.0000x reference)
//
#include <hip/hip_runtime.h>
#include <hip/hip_bf16.h>

#define B_   2
#define T_   2048
#define D_   1024
#define NH_  16
#define HD_  64
#define HID_ 4096
#define CD_  1024
#define SIX_D (6*D_)

typedef __bf16 bf16x8 __attribute__((ext_vector_type(8)));
typedef float  f32x4  __attribute__((ext_vector_type(4)));
typedef float  f32x16 __attribute__((ext_vector_type(16)));

__device__ __forceinline__ unsigned short f2bf(float f){
  union { float f; unsigned u; } v; v.f = f;
  unsigned r = v.u + 0x7FFFu + ((v.u >> 16) & 1u);
  return (unsigned short)(r >> 16);
}
__device__ __forceinline__ float bf2f(unsigned short u){
  union { unsigned x; float f; } v; v.x = ((unsigned)u) << 16; return v.f;
}

__device__ __forceinline__ void gl_lds16(const void* g, void* l){
  __builtin_amdgcn_global_load_lds(
      (__attribute__((address_space(1))) void*)const_cast<void*>(g),
      (__attribute__((address_space(3))) void*)l, 16, 0, 0);
}

// ---------------- all weights fp32 -> bf16, single launch ----------------
__global__ void k_conv_all(const float* __restrict__ s0, const float* __restrict__ s1,
                           const float* __restrict__ s2, const float* __restrict__ s3,
                           unsigned short* __restrict__ d0, unsigned short* __restrict__ d1,
                           unsigned short* __restrict__ d2, unsigned short* __restrict__ d3){
  int bid = blockIdx.x;
  const float* s; unsigned short* d; int base;
  if (bid < 3072)      { s = s0; d = d0; base = bid; }
  else if (bid < 4096) { s = s1; d = d1; base = bid - 3072; }
  else if (bid < 12288){ s = s2; d = d2; base = bid - 4096; }
  else                 { s = s3; d = d3; base = bid - 12288; }
  int i = base*256 + threadIdx.x;
  float4 v = reinterpret_cast<const float4*>(s)[i];
  ushort4 o;
  o.x = f2bf(v.x); o.y = f2bf(v.y); o.z = f2bf(v.z); o.w = f2bf(v.w);
  reinterpret_cast<ushort4*>(d)[i] = o;
}

// ---------------- ada = silu(cond) @ ada_w.T + ada_b ----------------
// coalesced: lanes iterate K (lane l reads w[col][l+64i]), shfl reduce; 16 cols/wave
__global__ void k_ada(const float* __restrict__ cond, const float* __restrict__ ada_w,
                      const float* __restrict__ ada_b, float* __restrict__ ada){
  __shared__ float sc[CD_];
  int b = blockIdx.y;
  int tid = threadIdx.x;
  for (int i = tid; i < CD_; i += 256){
    float c = cond[b*CD_ + i];
    sc[i] = c / (1.f + __expf(-c));
  }
  __syncthreads();
  int wave = tid >> 6, lane = tid & 63;
  int colbase = blockIdx.x*64 + wave*16;
  #pragma unroll
  for (int c = 0; c < 16; c++){
    int col = colbase + c;
    const float* wr = ada_w + (size_t)col*CD_;
    float acc = 0.f;
    #pragma unroll
    for (int i = 0; i < 16; i++)
      acc += sc[lane + 64*i] * wr[lane + 64*i];
    #pragma unroll
    for (int m = 32; m > 0; m >>= 1) acc += __shfl_xor(acc, m, 64);
    if (lane == 0) ada[b*SIX_D + col] = acc + ada_b[col];
  }
}

// ---------------- rmsnorm + modulate -> bf16 ----------------
__global__ void k_norm_mod(const float* __restrict__ x, const float* __restrict__ w,
                           const float* __restrict__ ada, int sh_off, int sc_off,
                           unsigned short* __restrict__ out){
  int row = blockIdx.x;           // b*T + t
  int b = row >> 11;              // / T_
  int tid = threadIdx.x;
  float4 xv = reinterpret_cast<const float4*>(x + (size_t)row*D_)[tid];
  float ss = xv.x*xv.x + xv.y*xv.y + xv.z*xv.z + xv.w*xv.w;
  #pragma unroll
  for (int m = 32; m > 0; m >>= 1) ss += __shfl_xor(ss, m, 64);
  __shared__ float red[4];
  int wave = tid >> 6;
  if ((tid & 63) == 0) red[wave] = ss;
  __syncthreads();
  float tot = red[0]+red[1]+red[2]+red[3];
  float rn = rsqrtf(tot * (1.f/(float)D_) + 1e-6f);
  float4 wv  = reinterpret_cast<const float4*>(w)[tid];
  float4 scv = reinterpret_cast<const float4*>(ada + b*SIX_D + sc_off)[tid];
  float4 shv = reinterpret_cast<const float4*>(ada + b*SIX_D + sh_off)[tid];
  ushort4 o;
  o.x = f2bf(xv.x*rn*wv.x*(1.f+scv.x)+shv.x);
  o.y = f2bf(xv.y*rn*wv.y*(1.f+scv.y)+shv.y);
  o.z = f2bf(xv.z*rn*wv.z*(1.f+scv.z)+shv.z);
  o.w = f2bf(xv.w*rn*wv.w*(1.f+scv.w)+shv.w);
  reinterpret_cast<ushort4*>(out + (size_t)row*D_)[tid] = o;
}

// ---------------- 128x128 GEMM: C = A(MxK) * W(NxK)^T ----------------
// counted-vmcnt schedule (T4): prefetch depth 2, never drain vmcnt to 0 in
// steady state; raw barriers; running stage pointers (no per-step addr calc).
enum { EPI_F32 = 0, EPI_RESID = 1, EPI_BF16 = 2 };

template<int EPI>
__launch_bounds__(256)
__global__ void k_gemm_bt(const unsigned short* __restrict__ A,
                          const unsigned short* __restrict__ W,
                          int M, int N, int K,
                          void* __restrict__ outp,
                          const float* __restrict__ resid,
                          const float* __restrict__ ada, int g_off,
                          const float* __restrict__ bias){
  __shared__ __align__(16) unsigned short As[2][128*32];
  __shared__ __align__(16) unsigned short Bs[2][128*32];
  const int tid = threadIdx.x;
  const int wave = tid >> 6, lane = tid & 63;
  const int wm = (wave >> 1)*64, wn = (wave & 1)*64;
  const int m0 = blockIdx.y*128, n0 = blockIdx.x*128;
  const int fr = lane & 15, fq = lane >> 4;
  const int sl = (fq ^ ((fr >> 1) & 3))*8;
  // staging geometry (computed once; pointers advance by 32 elems/step)
  const int r0 = tid >> 2, c0 = tid & 3;
  const int g0 = c0 ^ ((r0 >> 1) & 3);
  const int r1 = r0 + 64;
  const int g1 = c0 ^ ((r1 >> 1) & 3);
  const unsigned short* gA0 = A + (size_t)(m0 + r0)*K + g0*8;
  const unsigned short* gA1 = A + (size_t)(m0 + r1)*K + g1*8;
  const unsigned short* gB0 = W + (size_t)(n0 + r0)*K + g0*8;
  const unsigned short* gB1 = W + (size_t)(n0 + r1)*K + g1*8;
  const int l0 = (tid & ~63)*8, l1 = ((256 + tid) & ~63)*8;
  f32x4 acc[4][4] = {};
  auto stage = [&](int buf){
    gl_lds16(gA0, &As[buf][l0]);
    gl_lds16(gA1, &As[buf][l1]);
    gl_lds16(gB0, &Bs[buf][l0]);
    gl_lds16(gB1, &Bs[buf][l1]);
    gA0 += 32; gA1 += 32; gB0 += 32; gB1 += 32;
  };
  stage(0); stage(1);
  const int NK = K >> 5;
  for (int t = 0; t < NK; t++){
    const int cur = t & 1;
    if (t < NK - 1) asm volatile("s_waitcnt vmcnt(4)" ::: "memory");
    else            asm volatile("s_waitcnt vmcnt(0)" ::: "memory");
    __builtin_amdgcn_s_barrier();
    bf16x8 af[4], bfr[4];
    #pragma unroll
    for (int i = 0; i < 4; i++){
      af[i]  = *(const bf16x8*)&As[cur][(wm + i*16 + fr)*32 + sl];
      bfr[i] = *(const bf16x8*)&Bs[cur][(wn + i*16 + fr)*32 + sl];
    }
    __builtin_amdgcn_s_setprio(1);
    #pragma unroll
    for (int i = 0; i < 4; i++)
      #pragma unroll
      for (int j = 0; j < 4; j++)
        acc[i][j] = __builtin_amdgcn_mfma_f32_16x16x32_bf16(af[i], bfr[j], acc[i][j], 0,0,0);
    __builtin_amdgcn_s_setprio(0);
    __builtin_amdgcn_s_barrier();   // all frag reads of buf[cur] consumed by MFMAs
    if (t + 2 < NK) stage(cur);     // safe overwrite after barrier
  }
  #pragma unroll
  for (int i = 0; i < 4; i++){
    #pragma unroll
    for (int j = 0; j < 4; j++){
      int col = n0 + wn + j*16 + fr;
      #pragma unroll
      for (int r = 0; r < 4; r++){
        int row = m0 + wm + i*16 + fq*4 + r;
        float v = acc[i][j][r];
        if (EPI == EPI_F32){
          ((float*)outp)[(size_t)row*N + col] = v;
        } else if (EPI == EPI_BF16){
          ((unsigned short*)outp)[(size_t)row*N + col] = f2bf(v);
        } else {
          int b = row >> 11;
          float g = ada[b*SIX_D + g_off + col];
          ((float*)outp)[(size_t)row*N + col] = resid[(size_t)row*N + col] + g*(v + bias[col]);
        }
      }
    }
  }
}

// ---------------- 64x128 GEMM (for N=1024 shapes: proj, fc2) ----------------
template<int EPI>
__launch_bounds__(256)
__global__ void k_gemm_bt64(const unsigned short* __restrict__ A,
                            const unsigned short* __restrict__ W,
                            int M, int N, int K,
                            void* __restrict__ outp,
                            const float* __restrict__ resid,
                            const float* __restrict__ ada, int g_off,
                            const float* __restrict__ bias){
  __shared__ __align__(16) unsigned short As[2][64*32];
  __shared__ __align__(16) unsigned short Bs[2][128*32];
  const int tid = threadIdx.x;
  const int wave = tid >> 6, lane = tid & 63;
  const int wm = (wave >> 1)*32, wn = (wave & 1)*64;
  const int m0 = blockIdx.y*64, n0 = blockIdx.x*128;
  const int fr = lane & 15, fq = lane >> 4;
  const int sl = (fq ^ ((fr >> 1) & 3))*8;
  const int r0 = tid >> 2, c0 = tid & 3;
  const int g0 = c0 ^ ((r0 >> 1) & 3);
  const int r1 = r0 + 64;
  const int g1 = c0 ^ ((r1 >> 1) & 3);
  const unsigned short* gA0 = A + (size_t)(m0 + r0)*K + g0*8;
  const unsigned short* gB0 = W + (size_t)(n0 + r0)*K + g0*8;
  const unsigned short* gB1 = W + (size_t)(n0 + r1)*K + g1*8;
  const int l0 = (tid & ~63)*8, l1 = ((256 + tid) & ~63)*8;
  f32x4 acc[2][4] = {};
  auto stage = [&](int buf){
    gl_lds16(gA0, &As[buf][l0]);
    gl_lds16(gB0, &Bs[buf][l0]);
    gl_lds16(gB1, &Bs[buf][l1]);
    gA0 += 32; gB0 += 32; gB1 += 32;
  };
  stage(0); stage(1);
  const int NK = K >> 5;
  for (int t = 0; t < NK; t++){
    const int cur = t & 1;
    if (t < NK - 1) asm volatile("s_waitcnt vmcnt(3)" ::: "memory");
    else            asm volatile("s_waitcnt vmcnt(0)" ::: "memory");
    __builtin_amdgcn_s_barrier();
    bf16x8 af[2], bfr[4];
    #pragma unroll
    for (int i = 0; i < 2; i++)
      af[i]  = *(const bf16x8*)&As[cur][(wm + i*16 + fr)*32 + sl];
    #pragma unroll
    for (int j = 0; j < 4; j++)
      bfr[j] = *(const bf16x8*)&Bs[cur][(wn + j*16 + fr)*32 + sl];
    __builtin_amdgcn_s_setprio(1);
    #pragma unroll
    for (int i = 0; i < 2; i++)
      #pragma unroll
      for (int j = 0; j < 4; j++)
        acc[i][j] = __builtin_amdgcn_mfma_f32_16x16x32_bf16(af[i], bfr[j], acc[i][j], 0,0,0);
    __builtin_amdgcn_s_setprio(0);
    __builtin_amdgcn_s_barrier();
    if (t + 2 < NK) stage(cur);
  }
  #pragma unroll
  for (int i = 0; i < 2; i++){
    #pragma unroll
    for (int j = 0; j < 4; j++){
      int col = n0 + wn + j*16 + fr;
      #pragma unroll
      for (int r = 0; r < 4; r++){
        int row = m0 + wm + i*16 + fq*4 + r;
        float v = acc[i][j][r];
        if (EPI == EPI_F32){
          ((float*)outp)[(size_t)row*N + col] = v;
        } else if (EPI == EPI_BF16){
          ((unsigned short*)outp)[(size_t)row*N + col] = f2bf(v);
        } else {
          int b = row >> 11;
          float g = ada[b*SIX_D + g_off + col];
          ((float*)outp)[(size_t)row*N + col] = resid[(size_t)row*N + col] + g*(v + bias[col]);
        }
      }
    }
  }
}

// ---------------- fc1: 512-thread 256x(64v+64g) tile, counted-vmcnt dbuf,
// fused SwiGLU -> bf16. 8 waves = 4M x 2N; 3 loads/thread/stage ----------------
__launch_bounds__(512)
__global__ void k_gemm_fc1(const unsigned short* __restrict__ A,
                           const unsigned short* __restrict__ W,   // (2*HID, D) bf16
                           const float* __restrict__ bias,          // (2*HID)
                           unsigned short* __restrict__ out){       // (B*T, HID) bf16
  __shared__ __align__(16) unsigned short As[2][256*32];
  __shared__ __align__(16) unsigned short Bv[2][64*32];
  __shared__ __align__(16) unsigned short Bg[2][64*32];
  const int K = D_;
  const int tid = threadIdx.x;
  const int wave = tid >> 6, lane = tid & 63;
  const int wr = wave >> 1, wc = wave & 1;
  const int m0 = blockIdx.y*256, n0 = blockIdx.x*64;
  const int fr = lane & 15, fq = lane >> 4;
  const int sl = (fq ^ ((fr >> 1) & 3))*8;
  // A staging: 2 passes of 512 threads cover 256 rows x 4 chunks
  const int ra0 = tid >> 2, ca = tid & 3;
  const int ga0 = ca ^ ((ra0 >> 1) & 3);
  const int ra1 = ra0 + 128;
  const int ga1 = ca ^ ((ra1 >> 1) & 3);
  const unsigned short* gA0 = A + (size_t)(m0 + ra0)*K + ga0*8;
  const unsigned short* gA1 = A + (size_t)(m0 + ra1)*K + ga1*8;
  const int la0 = (tid & ~63)*8, la1 = ((512 + tid) & ~63)*8;
  // B staging: threads 0-255 -> Bv, 256-511 -> Bg (wave-uniform split)
  const int tb = tid & 255;
  const int rb = tb >> 2, cb = tb & 3;
  const int gb = cb ^ ((rb >> 1) & 3);
  const unsigned short* gB = W + (size_t)((tid < 256 ? 0 : HID_) + n0 + rb)*K + gb*8;
  const int lb = (tb & ~63)*8;
  f32x4 accv[4][2] = {}, accg[4][2] = {};
  auto stage = [&](int buf){
    gl_lds16(gA0, &As[buf][la0]);
    gl_lds16(gA1, &As[buf][la1]);
    gl_lds16(gB, (tid < 256) ? &Bv[buf][lb] : &Bg[buf][lb]);
    gA0 += 32; gA1 += 32; gB += 32;
  };
  stage(0); stage(1);
  const int NK = K >> 5;
  for (int t = 0; t < NK; t++){
    const int cur = t & 1;
    if (t < NK - 1) asm volatile("s_waitcnt vmcnt(3)" ::: "memory");
    else            asm volatile("s_waitcnt vmcnt(0)" ::: "memory");
    __builtin_amdgcn_s_barrier();
    bf16x8 af[4], bv[2], bg[2];
    #pragma unroll
    for (int i = 0; i < 4; i++)
      af[i] = *(const bf16x8*)&As[cur][(wr*64 + i*16 + fr)*32 + sl];
    #pragma unroll
    for (int j = 0; j < 2; j++){
      bv[j] = *(const bf16x8*)&Bv[cur][(wc*32 + j*16 + fr)*32 + sl];
      bg[j] = *(const bf16x8*)&Bg[cur][(wc*32 + j*16 + fr)*32 + sl];
    }
    __builtin_amdgcn_s_setprio(1);
    #pragma unroll
    for (int i = 0; i < 4; i++)
      #pragma unroll
      for (int j = 0; j < 2; j++){
        accv[i][j] = __builtin_amdgcn_mfma_f32_16x16x32_bf16(af[i], bv[j], accv[i][j], 0,0,0);
        accg[i][j] = __builtin_amdgcn_mfma_f32_16x16x32_bf16(af[i], bg[j], accg[i][j], 0,0,0);
      }
    __builtin_amdgcn_s_setprio(0);
    __builtin_amdgcn_s_barrier();
    if (t + 2 < NK) stage(cur);
  }
  #pragma unroll
  for (int i = 0; i < 4; i++){
    #pragma unroll
    for (int j = 0; j < 2; j++){
      int col = n0 + wc*32 + j*16 + fr;
      #pragma unroll
      for (int r = 0; r < 4; r++){
        int row = m0 + wr*64 + i*16 + fq*4 + r;
        float vv = accv[i][j][r] + bias[col];
        float gg = accg[i][j][r] + bias[HID_ + col];
        float h = vv * (gg / (1.f + __expf(-gg)));
        out[(size_t)row*HID_ + col] = f2bf(h);
      }
    }
  }
}

// ---------------- qkv(bf16) -> q,k with per-head rmsnorm + rope -> bf16 (B,NH,T,HD) ----------------
// 256-thread blocks, 4 heads per block (one per wave)
__global__ void k_qkv_post(const unsigned short* __restrict__ qkv,
                           const float* __restrict__ qw, const float* __restrict__ kw,
                           const int* __restrict__ wptr,
                           unsigned short* __restrict__ q, unsigned short* __restrict__ k){
  int idx = blockIdx.x*4 + (threadIdx.x >> 6);   // (b*T + t)*NH + h
  int h = idx & (NH_-1);
  int t = (idx >> 4) & (T_-1);
  int b = idx >> 15;
  int d = threadIdx.x & 63;
  const unsigned short* base = qkv + (size_t)(b*T_ + t)*3072;
  float qv = bf2f(base[h*64 + d]);
  float kv = bf2f(base[1024 + h*64 + d]);
  float sq = qv*qv, sk = kv*kv;
  #pragma unroll
  for (int m = 32; m > 0; m >>= 1){ sq += __shfl_xor(sq, m, 64); sk += __shfl_xor(sk, m, 64); }
  qv *= rsqrtf(sq*(1.f/64.f) + 1e-6f) * qw[d];
  kv *= rsqrtf(sk*(1.f/64.f) + 1e-6f) * kw[d];
  int width = wptr[0];
  int yy = t / width, xx = t - yy*width;
  int coord = (d < 32) ? yy : xx;
  int fi = (d & 31) >> 1;
  float ifreq = __expf(-(float)fi * (9.210340371976184f/16.f));  // 10000^(-fi/16)
  float ang = (float)coord * ifreq;
  float cs = cosf(ang), sn = sinf(ang);
  float pq = __shfl_xor(qv, 1, 64);
  float pk = __shfl_xor(kv, 1, 64);
  float rq = (d & 1) ? pq : -pq;
  float rk = (d & 1) ? pk : -pk;
  qv = qv*cs + rq*sn;
  kv = kv*cs + rk*sn;
  size_t o = ((size_t)(b*NH_ + h)*T_ + t)*64 + d;
  q[o] = f2bf(qv); k[o] = f2bf(kv);
}

// ---------------- V transpose: qkv bf16 (b,t, 2048 + h*64+d) -> vt bf16 (b,h,d,t) ----------------
__global__ void k_vtrans(const unsigned short* __restrict__ qkv, unsigned short* __restrict__ vt){
  __shared__ __align__(16) unsigned short TT[64*64];  // [d][t], groups swizzled
  int bh = blockIdx.y, t0 = blockIdx.x*64;
  int b = bh >> 4, h = bh & 15;
  int tid = threadIdx.x;
  #pragma unroll
  for (int it = 0; it < 2; it++){
    int i2 = it*256 + tid;
    int t = i2 >> 3, c8 = (i2 & 7)*8;
    union { uint4 v; unsigned short u[8]; } ld;
    ld.v = *(const uint4*)(qkv + (size_t)(b*T_ + t0 + t)*3072 + 2048 + h*64 + c8);
    #pragma unroll
    for (int e = 0; e < 8; e++){
      int c = c8 + e;
      int gp = (t >> 3) ^ ((c >> 2) & 7);
      TT[c*64 + gp*8 + (t & 7)] = ld.u[e];
    }
  }
  __syncthreads();
  #pragma unroll
  for (int it = 0; it < 2; it++){
    int i2 = it*256 + tid;
    int d = i2 >> 3, g = i2 & 7;
    int gp = g ^ ((d >> 2) & 7);
    *(uint4*)(vt + ((size_t)(bh*64 + d)*T_ + t0 + g*8)) = *(const uint4*)&TT[d*64 + gp*8];
  }
}

// ---------------- flash attention v3 (verified r2): swapped-QK 32x32x16,
// in-register softmax, LDS-staged K/V with dbuf + stage-ahead ----------------
__launch_bounds__(128, 2)
__global__ void k_attn(const unsigned short* __restrict__ q,
                       const unsigned short* __restrict__ k,
                       const unsigned short* __restrict__ vt,
                       unsigned short* __restrict__ out){     // (B,T,D) bf16
  __shared__ __align__(16) unsigned short Kl[2][64*64];   // [row=k-pos][64 elems], chunks swizzled
  __shared__ __align__(16) unsigned short Vl[2][64*64];   // [row=d]    [64 t],     chunks swizzled
  const int tid  = threadIdx.x;
  const int wave = tid >> 6;      // 0..1
  const int lane = tid & 63;
  const int ln   = lane & 31;
  const int hi   = lane >> 5;
  const int id = blockIdx.x;
  const int bh = id & 31;                        // id%8==bh%8 -> head-local XCD
  const int q0 = (id >> 5)*64 + wave*32;         // this wave's 32 q-rows

  bf16x8 qf[4];
  {
    const unsigned short* qp = q + ((size_t)bh*T_ + q0 + ln)*HD_ + hi*8;
    #pragma unroll
    for (int kk = 0; kk < 4; kk++)
      qf[kk] = *(const bf16x8*)(qp + kk*16);
  }
  const unsigned short* kg = k  + (size_t)bh*T_*HD_;
  const unsigned short* vg = vt + (size_t)bh*HD_*T_;

  auto stage = [&](int buf, int kt){
    #pragma unroll
    for (int rr = 0; rr < 4; rr++){
      int idx = rr*128 + tid;
      int row = idx >> 3, c = idx & 7;
      int g = c ^ (row & 7);
      gl_lds16(kg + (size_t)(kt + row)*HD_ + g*8, &Kl[buf][(idx & ~63)*8]);
      gl_lds16(vg + (size_t)row*T_ + kt + g*8,    &Vl[buf][(idx & ~63)*8]);
    }
  };

  f32x16 o0 = {}, o1 = {};
  float ls[4] = {};
  const int vr0 = ln*64, vr1 = (32 + ln)*64;
  const int sw = ln & 7;

  stage(0, 0);
  __syncthreads();

  for (int t = 0; t < T_/64; t++){
    const int cur = t & 1, nxt = cur ^ 1;
    if (t + 1 < T_/64) stage(nxt, (t + 1)*64);
    const unsigned short* Kc = Kl[cur];
    const unsigned short* Vc = Vl[cur];
    #pragma unroll
    for (int s2 = 0; s2 < 2; s2++){
      bf16x8 kf[4];
      const int kb = (s2*32 + ln)*64;
      #pragma unroll
      for (int kk = 0; kk < 4; kk++){
        int ch = (kk*2 + hi) ^ sw;
        kf[kk] = *(const bf16x8*)&Kc[kb + ch*8];
      }
      f32x16 sa = {}, sb = {};
      __builtin_amdgcn_s_setprio(1);
      sa = __builtin_amdgcn_mfma_f32_32x32x16_bf16(kf[0], qf[0], sa, 0, 0, 0);
      sb = __builtin_amdgcn_mfma_f32_32x32x16_bf16(kf[1], qf[1], sb, 0, 0, 0);
      sa = __builtin_amdgcn_mfma_f32_32x32x16_bf16(kf[2], qf[2], sa, 0, 0, 0);
      sb = __builtin_amdgcn_mfma_f32_32x32x16_bf16(kf[3], qf[3], sb, 0, 0, 0);
      __builtin_amdgcn_s_setprio(0);
      union { uint2 u2[2]; bf16x8 v; } v0f[2], v1f[2];
      #pragma unroll
      for (int c = 0; c < 2; c++){
        int chA = (s2*4 + c*2)     ^ sw;
        int chB = (s2*4 + c*2 + 1) ^ sw;
        v0f[c].u2[0] = *(const uint2*)&Vc[vr0 + chA*8 + hi*4];
        v0f[c].u2[1] = *(const uint2*)&Vc[vr0 + chB*8 + hi*4];
        v1f[c].u2[0] = *(const uint2*)&Vc[vr1 + chA*8 + hi*4];
        v1f[c].u2[1] = *(const uint2*)&Vc[vr1 + chB*8 + hi*4];
      }
      f32x16 sv = sa + sb;
      float p[16];
      #pragma unroll
      for (int r = 0; r < 16; r++)
        p[r] = __expf(fminf(sv[r]*0.125f, 30.f));
      union { __bf16 h[16]; bf16x8 v[2]; } pa;
      #pragma unroll
      for (int r = 0; r < 16; r++){
        pa.h[r] = (__bf16)p[r];
        ls[r & 3] += p[r];
      }
      __builtin_amdgcn_s_setprio(1);
      o0 = __builtin_amdgcn_mfma_f32_32x32x16_bf16(pa.v[0], v0f[0].v, o0, 0, 0, 0);
      o1 = __builtin_amdgcn_mfma_f32_32x32x16_bf16(pa.v[0], v1f[0].v, o1, 0, 0, 0);
      o0 = __builtin_amdgcn_mfma_f32_32x32x16_bf16(pa.v[1], v0f[1].v, o0, 0, 0, 0);
      o1 = __builtin_amdgcn_mfma_f32_32x32x16_bf16(pa.v[1], v1f[1].v, o1, 0, 0, 0);
      __builtin_amdgcn_s_setprio(0);
    }
    __syncthreads();
  }

  float lsum = ls[0] + ls[1] + ls[2] + ls[3];
  lsum += __shfl_xor(lsum, 32, 64);
  float inv = 1.f / lsum;
  const int b = bh >> 4, h = bh & 15;
  unsigned short* ob = out + ((size_t)(b*T_ + q0))*D_ + h*64 + ln;
  #pragma unroll
  for (int r = 0; r < 16; r++){
    int qr = (r & 3) + 8*(r >> 2) + 4*hi;
    float invr = __shfl(inv, qr, 64);
    unsigned short* op = ob + (size_t)qr*D_;
    op[0]  = f2bf(o0[r]*invr);
    op[32] = f2bf(o1[r]*invr);
  }
}

extern "C" void kernel_launch(void* const* d_in, const int* in_sizes, int n_in,
                              void* d_out, int out_size, void* d_ws, size_t ws_size,
                              hipStream_t stream){
  const float* x      = (const float*)d_in[0];
  const float* cond   = (const float*)d_in[1];
  const float* norm1w = (const float*)d_in[2];
  const float* qkv_w  = (const float*)d_in[3];
  const float* q_nw   = (const float*)d_in[4];
  const float* k_nw   = (const float*)d_in[5];
  const float* proj_w = (const float*)d_in[6];
  const float* proj_b = (const float*)d_in[7];
  const float* norm2w = (const float*)d_in[8];
  const float* fc1_w  = (const float*)d_in[9];
  const float* fc1_b  = (const float*)d_in[10];
  const float* fc2_w  = (const float*)d_in[11];
  const float* fc2_b  = (const float*)d_in[12];
  const float* ada_w  = (const float*)d_in[13];
  const float* ada_b  = (const float*)d_in[14];
  const int*   wptr   = (const int*)d_in[16];
  float* out = (float*)d_out;

  char* ws = (char*)d_ws;
  size_t off = 0;
  auto alloc = [&](size_t bytes)->void*{
    void* p = ws + off; off += (bytes + 255) & ~(size_t)255; return p;
  };
  unsigned short* w_qkv  = (unsigned short*)alloc(3072ull*1024*2);
  unsigned short* w_proj = (unsigned short*)alloc(1024ull*1024*2);
  unsigned short* w_fc1  = (unsigned short*)alloc(8192ull*1024*2);
  unsigned short* w_fc2  = (unsigned short*)alloc(1024ull*4096*2);
  float* ada             = (float*)alloc((size_t)B_*SIX_D*4);
  unsigned short* h1     = (unsigned short*)alloc(4096ull*1024*2);
  // region R: qkv_out bf16 (25 MB) lives until k_vtrans; afterwards reused
  char* R                = (char*)alloc(4096ull*3072*4);
  unsigned short* qkv_out= (unsigned short*)R;
  unsigned short* attn_o = (unsigned short*)R;                       // 8.39 MB (after qkv dead)
  float* x1              = (float*)(R + (size_t)B_*T_*D_*2);         // 16.78 MB
  unsigned short* qb     = (unsigned short*)alloc(32ull*2048*64*2);
  unsigned short* kb     = (unsigned short*)alloc(32ull*2048*64*2);
  unsigned short* vt     = (unsigned short*)alloc(32ull*64*2048*2);
  unsigned short* mlp    = (unsigned short*)alloc(4096ull*4096*2);
  (void)ws_size; (void)in_sizes; (void)n_in; (void)out_size;

  k_conv_all<<<16384, 256, 0, stream>>>(qkv_w, proj_w, fc1_w, fc2_w, w_qkv, w_proj, w_fc1, w_fc2);

  k_ada<<<dim3(SIX_D/64, B_), 256, 0, stream>>>(cond, ada_w, ada_b, ada);
  k_norm_mod<<<B_*T_, 256, 0, stream>>>(x, norm1w, ada, 0, D_, h1);
  k_gemm_bt<EPI_BF16><<<dim3(3072/128, 4096/128), 256, 0, stream>>>(
      h1, w_qkv, B_*T_, 3*D_, D_, qkv_out, nullptr, nullptr, 0, nullptr);
  k_qkv_post<<<B_*T_*NH_/4, 256, 0, stream>>>(qkv_out, q_nw, k_nw, wptr, qb, kb);
  k_vtrans<<<dim3(T_/64, 32), 256, 0, stream>>>(qkv_out, vt);
  k_attn<<<1024, 128, 0, stream>>>(qb, kb, vt, attn_o);
  k_gemm_bt64<EPI_RESID><<<dim3(1024/128, 4096/64), 256, 0, stream>>>(
      attn_o, w_proj, B_*T_, D_, D_, x1, x, ada, 2*D_, proj_b);
  k_norm_mod<<<B_*T_, 256, 0, stream>>>(x1, norm2w, ada, 3*D_, 4*D_, h1);
  k_gemm_fc1<<<dim3(HID_/64, B_*T_/256), 512, 0, stream>>>(h1, w_fc1, fc1_b, mlp);
  k_gemm_bt64<EPI_RESID><<<dim3(1024/128, 4096/64), 256, 0, stream>>>(
      mlp, w_fc2, B_*T_, D_, HID_, out, x1, ada, 5*D_, fc2_b);
}

// Round 6
// 464.959 us; speedup vs baseline: 1.0647x; 1.0647x over previous
//
#include <hip/hip_runtime.h>
#include <hip/hip_bf16.h>

#define B_   2
#define T_   2048
#define D_   1024
#define NH_  16
#define HD_  64
#define HID_ 4096
#define CD_  1024
#define SIX_D (6*D_)

typedef __bf16 bf16x8 __attribute__((ext_vector_type(8)));
typedef float  f32x4  __attribute__((ext_vector_type(4)));
typedef float  f32x16 __attribute__((ext_vector_type(16)));

__device__ __forceinline__ unsigned short f2bf(float f){
  union { float f; unsigned u; } v; v.f = f;
  unsigned r = v.u + 0x7FFFu + ((v.u >> 16) & 1u);
  return (unsigned short)(r >> 16);
}
__device__ __forceinline__ float bf2f(unsigned short u){
  union { unsigned x; float f; } v; v.x = ((unsigned)u) << 16; return v.f;
}

__device__ __forceinline__ void gl_lds16(const void* g, void* l){
  __builtin_amdgcn_global_load_lds(
      (__attribute__((address_space(1))) void*)const_cast<void*>(g),
      (__attribute__((address_space(3))) void*)l, 16, 0, 0);
}

// ---------------- all weights fp32 -> bf16, single launch ----------------
__global__ void k_conv_all(const float* __restrict__ s0, const float* __restrict__ s1,
                           const float* __restrict__ s2, const float* __restrict__ s3,
                           unsigned short* __restrict__ d0, unsigned short* __restrict__ d1,
                           unsigned short* __restrict__ d2, unsigned short* __restrict__ d3){
  int bid = blockIdx.x;
  const float* s; unsigned short* d; int base;
  if (bid < 3072)      { s = s0; d = d0; base = bid; }
  else if (bid < 4096) { s = s1; d = d1; base = bid - 3072; }
  else if (bid < 12288){ s = s2; d = d2; base = bid - 4096; }
  else                 { s = s3; d = d3; base = bid - 12288; }
  int i = base*256 + threadIdx.x;
  float4 v = reinterpret_cast<const float4*>(s)[i];
  ushort4 o;
  o.x = f2bf(v.x); o.y = f2bf(v.y); o.z = f2bf(v.z); o.w = f2bf(v.w);
  reinterpret_cast<ushort4*>(d)[i] = o;
}

// ---------------- ada = silu(cond) @ ada_w.T + ada_b ----------------
// coalesced: lanes iterate K (lane l reads w[col][l+64i]), shfl reduce; 16 cols/wave
__global__ void k_ada(const float* __restrict__ cond, const float* __restrict__ ada_w,
                      const float* __restrict__ ada_b, float* __restrict__ ada){
  __shared__ float sc[CD_];
  int b = blockIdx.y;
  int tid = threadIdx.x;
  for (int i = tid; i < CD_; i += 256){
    float c = cond[b*CD_ + i];
    sc[i] = c / (1.f + __expf(-c));
  }
  __syncthreads();
  int wave = tid >> 6, lane = tid & 63;
  int colbase = blockIdx.x*64 + wave*16;
  #pragma unroll
  for (int c = 0; c < 16; c++){
    int col = colbase + c;
    const float* wr = ada_w + (size_t)col*CD_;
    float acc = 0.f;
    #pragma unroll
    for (int i = 0; i < 16; i++)
      acc += sc[lane + 64*i] * wr[lane + 64*i];
    #pragma unroll
    for (int m = 32; m > 0; m >>= 1) acc += __shfl_xor(acc, m, 64);
    if (lane == 0) ada[b*SIX_D + col] = acc + ada_b[col];
  }
}

// ---------------- rmsnorm + modulate -> bf16 ----------------
__global__ void k_norm_mod(const float* __restrict__ x, const float* __restrict__ w,
                           const float* __restrict__ ada, int sh_off, int sc_off,
                           unsigned short* __restrict__ out){
  int row = blockIdx.x;           // b*T + t
  int b = row >> 11;              // / T_
  int tid = threadIdx.x;
  float4 xv = reinterpret_cast<const float4*>(x + (size_t)row*D_)[tid];
  float ss = xv.x*xv.x + xv.y*xv.y + xv.z*xv.z + xv.w*xv.w;
  #pragma unroll
  for (int m = 32; m > 0; m >>= 1) ss += __shfl_xor(ss, m, 64);
  __shared__ float red[4];
  int wave = tid >> 6;
  if ((tid & 63) == 0) red[wave] = ss;
  __syncthreads();
  float tot = red[0]+red[1]+red[2]+red[3];
  float rn = rsqrtf(tot * (1.f/(float)D_) + 1e-6f);
  float4 wv  = reinterpret_cast<const float4*>(w)[tid];
  float4 scv = reinterpret_cast<const float4*>(ada + b*SIX_D + sc_off)[tid];
  float4 shv = reinterpret_cast<const float4*>(ada + b*SIX_D + sh_off)[tid];
  ushort4 o;
  o.x = f2bf(xv.x*rn*wv.x*(1.f+scv.x)+shv.x);
  o.y = f2bf(xv.y*rn*wv.y*(1.f+scv.y)+shv.y);
  o.z = f2bf(xv.z*rn*wv.z*(1.f+scv.z)+shv.z);
  o.w = f2bf(xv.w*rn*wv.w*(1.f+scv.w)+shv.w);
  reinterpret_cast<ushort4*>(out + (size_t)row*D_)[tid] = o;
}

// ---------------- 128x128 GEMM: C = A(MxK) * W(NxK)^T ----------------
// counted-vmcnt schedule, prefetch depth 3 (loads get 2 compute phases to land)
enum { EPI_F32 = 0, EPI_RESID = 1, EPI_BF16 = 2 };

template<int EPI>
__launch_bounds__(256)
__global__ void k_gemm_bt(const unsigned short* __restrict__ A,
                          const unsigned short* __restrict__ W,
                          int M, int N, int K,
                          void* __restrict__ outp,
                          const float* __restrict__ resid,
                          const float* __restrict__ ada, int g_off,
                          const float* __restrict__ bias){
  __shared__ __align__(16) unsigned short As[3][128*32];
  __shared__ __align__(16) unsigned short Bs[3][128*32];
  const int tid = threadIdx.x;
  const int wave = tid >> 6, lane = tid & 63;
  const int wm = (wave >> 1)*64, wn = (wave & 1)*64;
  const int m0 = blockIdx.y*128, n0 = blockIdx.x*128;
  const int fr = lane & 15, fq = lane >> 4;
  const int sl = (fq ^ ((fr >> 1) & 3))*8;
  const int r0 = tid >> 2, c0 = tid & 3;
  const int g0 = c0 ^ ((r0 >> 1) & 3);
  const int r1 = r0 + 64;
  const int g1 = c0 ^ ((r1 >> 1) & 3);
  const unsigned short* gA0 = A + (size_t)(m0 + r0)*K + g0*8;
  const unsigned short* gA1 = A + (size_t)(m0 + r1)*K + g1*8;
  const unsigned short* gB0 = W + (size_t)(n0 + r0)*K + g0*8;
  const unsigned short* gB1 = W + (size_t)(n0 + r1)*K + g1*8;
  const int l0 = (tid & ~63)*8, l1 = ((256 + tid) & ~63)*8;
  f32x4 acc[4][4] = {};
  auto stage = [&](int buf){
    gl_lds16(gA0, &As[buf][l0]);
    gl_lds16(gA1, &As[buf][l1]);
    gl_lds16(gB0, &Bs[buf][l0]);
    gl_lds16(gB1, &Bs[buf][l1]);
    gA0 += 32; gA1 += 32; gB0 += 32; gB1 += 32;
  };
  stage(0); stage(1); stage(2);
  const int NK = K >> 5;
  int cur = 0;
  for (int t = 0; t < NK; t++){
    if (t < NK - 2)      asm volatile("s_waitcnt vmcnt(8)" ::: "memory");
    else if (t < NK - 1) asm volatile("s_waitcnt vmcnt(4)" ::: "memory");
    else                 asm volatile("s_waitcnt vmcnt(0)" ::: "memory");
    __builtin_amdgcn_s_barrier();
    bf16x8 af[4], bfr[4];
    #pragma unroll
    for (int i = 0; i < 4; i++){
      af[i]  = *(const bf16x8*)&As[cur][(wm + i*16 + fr)*32 + sl];
      bfr[i] = *(const bf16x8*)&Bs[cur][(wn + i*16 + fr)*32 + sl];
    }
    __builtin_amdgcn_s_setprio(1);
    #pragma unroll
    for (int i = 0; i < 4; i++)
      #pragma unroll
      for (int j = 0; j < 4; j++)
        acc[i][j] = __builtin_amdgcn_mfma_f32_16x16x32_bf16(af[i], bfr[j], acc[i][j], 0,0,0);
    __builtin_amdgcn_s_setprio(0);
    __builtin_amdgcn_s_barrier();   // buf[cur] fully consumed
    if (t + 3 < NK) stage(cur);     // stage tile t+3 into the buffer just freed
    cur = (cur == 2) ? 0 : cur + 1;
  }
  #pragma unroll
  for (int i = 0; i < 4; i++){
    #pragma unroll
    for (int j = 0; j < 4; j++){
      int col = n0 + wn + j*16 + fr;
      #pragma unroll
      for (int r = 0; r < 4; r++){
        int row = m0 + wm + i*16 + fq*4 + r;
        float v = acc[i][j][r];
        if (EPI == EPI_F32){
          ((float*)outp)[(size_t)row*N + col] = v;
        } else if (EPI == EPI_BF16){
          ((unsigned short*)outp)[(size_t)row*N + col] = f2bf(v);
        } else {
          int b = row >> 11;
          float g = ada[b*SIX_D + g_off + col];
          ((float*)outp)[(size_t)row*N + col] = resid[(size_t)row*N + col] + g*(v + bias[col]);
        }
      }
    }
  }
}

// ---------------- 64x128 GEMM (proj, fc2), prefetch depth 3 ----------------
template<int EPI>
__launch_bounds__(256)
__global__ void k_gemm_bt64(const unsigned short* __restrict__ A,
                            const unsigned short* __restrict__ W,
                            int M, int N, int K,
                            void* __restrict__ outp,
                            const float* __restrict__ resid,
                            const float* __restrict__ ada, int g_off,
                            const float* __restrict__ bias){
  __shared__ __align__(16) unsigned short As[3][64*32];
  __shared__ __align__(16) unsigned short Bs[3][128*32];
  const int tid = threadIdx.x;
  const int wave = tid >> 6, lane = tid & 63;
  const int wm = (wave >> 1)*32, wn = (wave & 1)*64;
  const int m0 = blockIdx.y*64, n0 = blockIdx.x*128;
  const int fr = lane & 15, fq = lane >> 4;
  const int sl = (fq ^ ((fr >> 1) & 3))*8;
  const int r0 = tid >> 2, c0 = tid & 3;
  const int g0 = c0 ^ ((r0 >> 1) & 3);
  const int r1 = r0 + 64;
  const int g1 = c0 ^ ((r1 >> 1) & 3);
  const unsigned short* gA0 = A + (size_t)(m0 + r0)*K + g0*8;
  const unsigned short* gB0 = W + (size_t)(n0 + r0)*K + g0*8;
  const unsigned short* gB1 = W + (size_t)(n0 + r1)*K + g1*8;
  const int l0 = (tid & ~63)*8, l1 = ((256 + tid) & ~63)*8;
  f32x4 acc[2][4] = {};
  auto stage = [&](int buf){
    gl_lds16(gA0, &As[buf][l0]);
    gl_lds16(gB0, &Bs[buf][l0]);
    gl_lds16(gB1, &Bs[buf][l1]);
    gA0 += 32; gB0 += 32; gB1 += 32;
  };
  stage(0); stage(1); stage(2);
  const int NK = K >> 5;
  int cur = 0;
  for (int t = 0; t < NK; t++){
    if (t < NK - 2)      asm volatile("s_waitcnt vmcnt(6)" ::: "memory");
    else if (t < NK - 1) asm volatile("s_waitcnt vmcnt(3)" ::: "memory");
    else                 asm volatile("s_waitcnt vmcnt(0)" ::: "memory");
    __builtin_amdgcn_s_barrier();
    bf16x8 af[2], bfr[4];
    #pragma unroll
    for (int i = 0; i < 2; i++)
      af[i]  = *(const bf16x8*)&As[cur][(wm + i*16 + fr)*32 + sl];
    #pragma unroll
    for (int j = 0; j < 4; j++)
      bfr[j] = *(const bf16x8*)&Bs[cur][(wn + j*16 + fr)*32 + sl];
    __builtin_amdgcn_s_setprio(1);
    #pragma unroll
    for (int i = 0; i < 2; i++)
      #pragma unroll
      for (int j = 0; j < 4; j++)
        acc[i][j] = __builtin_amdgcn_mfma_f32_16x16x32_bf16(af[i], bfr[j], acc[i][j], 0,0,0);
    __builtin_amdgcn_s_setprio(0);
    __builtin_amdgcn_s_barrier();
    if (t + 3 < NK) stage(cur);
    cur = (cur == 2) ? 0 : cur + 1;
  }
  #pragma unroll
  for (int i = 0; i < 2; i++){
    #pragma unroll
    for (int j = 0; j < 4; j++){
      int col = n0 + wn + j*16 + fr;
      #pragma unroll
      for (int r = 0; r < 4; r++){
        int row = m0 + wm + i*16 + fq*4 + r;
        float v = acc[i][j][r];
        if (EPI == EPI_F32){
          ((float*)outp)[(size_t)row*N + col] = v;
        } else if (EPI == EPI_BF16){
          ((unsigned short*)outp)[(size_t)row*N + col] = f2bf(v);
        } else {
          int b = row >> 11;
          float g = ada[b*SIX_D + g_off + col];
          ((float*)outp)[(size_t)row*N + col] = resid[(size_t)row*N + col] + g*(v + bias[col]);
        }
      }
    }
  }
}

// ---------------- fc1 dual 128x(64+64) with fused SwiGLU -> bf16 (r4-verified) ----------------
__launch_bounds__(256)
__global__ void k_gemm_fc1(const unsigned short* __restrict__ A,
                           const unsigned short* __restrict__ W,   // (2*HID, D) bf16
                           const float* __restrict__ bias,          // (2*HID)
                           unsigned short* __restrict__ out){       // (B*T, HID) bf16
  __shared__ __align__(16) unsigned short As[2][128*32];
  __shared__ __align__(16) unsigned short Bv[2][64*32];
  __shared__ __align__(16) unsigned short Bg[2][64*32];
  const int K = D_;
  const int tid = threadIdx.x;
  const int wave = tid >> 6, lane = tid & 63;
  const int wm = (wave >> 1)*64, wn = (wave & 1)*32;
  const int m0 = blockIdx.y*128, n0 = blockIdx.x*64;
  const int fr = lane & 15, fq = lane >> 4;
  const int sl = (fq ^ ((fr >> 1) & 3))*8;
  const int r0 = tid >> 2, c0 = tid & 3;
  const int g0 = c0 ^ ((r0 >> 1) & 3);
  const int r1 = r0 + 64;
  const int g1 = c0 ^ ((r1 >> 1) & 3);
  const unsigned short* gA0 = A + (size_t)(m0 + r0)*K + g0*8;
  const unsigned short* gA1 = A + (size_t)(m0 + r1)*K + g1*8;
  const unsigned short* gBv = W + (size_t)(n0 + r0)*K + g0*8;
  const unsigned short* gBg = W + (size_t)(HID_ + n0 + r0)*K + g0*8;
  const int l0 = (tid & ~63)*8, l1 = ((256 + tid) & ~63)*8;
  f32x4 accv[4][2] = {}, accg[4][2] = {};
  auto stage = [&](int buf){
    gl_lds16(gA0, &As[buf][l0]);
    gl_lds16(gA1, &As[buf][l1]);
    gl_lds16(gBv, &Bv[buf][l0]);
    gl_lds16(gBg, &Bg[buf][l0]);
    gA0 += 32; gA1 += 32; gBv += 32; gBg += 32;
  };
  stage(0); stage(1);
  const int NK = K >> 5;
  for (int t = 0; t < NK; t++){
    const int cur = t & 1;
    if (t < NK - 1) asm volatile("s_waitcnt vmcnt(4)" ::: "memory");
    else            asm volatile("s_waitcnt vmcnt(0)" ::: "memory");
    __builtin_amdgcn_s_barrier();
    bf16x8 af[4], bv[2], bg[2];
    #pragma unroll
    for (int i = 0; i < 4; i++)
      af[i] = *(const bf16x8*)&As[cur][(wm + i*16 + fr)*32 + sl];
    #pragma unroll
    for (int j = 0; j < 2; j++){
      bv[j] = *(const bf16x8*)&Bv[cur][(wn + j*16 + fr)*32 + sl];
      bg[j] = *(const bf16x8*)&Bg[cur][(wn + j*16 + fr)*32 + sl];
    }
    __builtin_amdgcn_s_setprio(1);
    #pragma unroll
    for (int i = 0; i < 4; i++)
      #pragma unroll
      for (int j = 0; j < 2; j++){
        accv[i][j] = __builtin_amdgcn_mfma_f32_16x16x32_bf16(af[i], bv[j], accv[i][j], 0,0,0);
        accg[i][j] = __builtin_amdgcn_mfma_f32_16x16x32_bf16(af[i], bg[j], accg[i][j], 0,0,0);
      }
    __builtin_amdgcn_s_setprio(0);
    __builtin_amdgcn_s_barrier();
    if (t + 2 < NK) stage(cur);
  }
  #pragma unroll
  for (int i = 0; i < 4; i++){
    #pragma unroll
    for (int j = 0; j < 2; j++){
      int col = n0 + wn + j*16 + fr;
      #pragma unroll
      for (int r = 0; r < 4; r++){
        int row = m0 + wm + i*16 + fq*4 + r;
        float vv = accv[i][j][r] + bias[col];
        float gg = accg[i][j][r] + bias[HID_ + col];
        float h = vv * (gg / (1.f + __expf(-gg)));
        out[(size_t)row*HID_ + col] = f2bf(h);
      }
    }
  }
}

// ---------------- qkv(bf16) -> q,k with per-head rmsnorm + rope -> bf16 (B,NH,T,HD) ----------------
// 256-thread blocks, 4 heads per block (one per wave)
__global__ void k_qkv_post(const unsigned short* __restrict__ qkv,
                           const float* __restrict__ qw, const float* __restrict__ kw,
                           const int* __restrict__ wptr,
                           unsigned short* __restrict__ q, unsigned short* __restrict__ k){
  int idx = blockIdx.x*4 + (threadIdx.x >> 6);   // (b*T + t)*NH + h
  int h = idx & (NH_-1);
  int t = (idx >> 4) & (T_-1);
  int b = idx >> 15;
  int d = threadIdx.x & 63;
  const unsigned short* base = qkv + (size_t)(b*T_ + t)*3072;
  float qv = bf2f(base[h*64 + d]);
  float kv = bf2f(base[1024 + h*64 + d]);
  float sq = qv*qv, sk = kv*kv;
  #pragma unroll
  for (int m = 32; m > 0; m >>= 1){ sq += __shfl_xor(sq, m, 64); sk += __shfl_xor(sk, m, 64); }
  qv *= rsqrtf(sq*(1.f/64.f) + 1e-6f) * qw[d];
  kv *= rsqrtf(sk*(1.f/64.f) + 1e-6f) * kw[d];
  int width = wptr[0];
  int yy = t / width, xx = t - yy*width;
  int coord = (d < 32) ? yy : xx;
  int fi = (d & 31) >> 1;
  float ifreq = __expf(-(float)fi * (9.210340371976184f/16.f));  // 10000^(-fi/16)
  float ang = (float)coord * ifreq;
  float cs = cosf(ang), sn = sinf(ang);
  float pq = __shfl_xor(qv, 1, 64);
  float pk = __shfl_xor(kv, 1, 64);
  float rq = (d & 1) ? pq : -pq;
  float rk = (d & 1) ? pk : -pk;
  qv = qv*cs + rq*sn;
  kv = kv*cs + rk*sn;
  size_t o = ((size_t)(b*NH_ + h)*T_ + t)*64 + d;
  q[o] = f2bf(qv); k[o] = f2bf(kv);
}

// ---------------- V transpose: qkv bf16 (b,t, 2048 + h*64+d) -> vt bf16 (b,h,d,t) ----------------
__global__ void k_vtrans(const unsigned short* __restrict__ qkv, unsigned short* __restrict__ vt){
  __shared__ __align__(16) unsigned short TT[64*64];  // [d][t], groups swizzled
  int bh = blockIdx.y, t0 = blockIdx.x*64;
  int b = bh >> 4, h = bh & 15;
  int tid = threadIdx.x;
  #pragma unroll
  for (int it = 0; it < 2; it++){
    int i2 = it*256 + tid;
    int t = i2 >> 3, c8 = (i2 & 7)*8;
    union { uint4 v; unsigned short u[8]; } ld;
    ld.v = *(const uint4*)(qkv + (size_t)(b*T_ + t0 + t)*3072 + 2048 + h*64 + c8);
    #pragma unroll
    for (int e = 0; e < 8; e++){
      int c = c8 + e;
      int gp = (t >> 3) ^ ((c >> 2) & 7);
      TT[c*64 + gp*8 + (t & 7)] = ld.u[e];
    }
  }
  __syncthreads();
  #pragma unroll
  for (int it = 0; it < 2; it++){
    int i2 = it*256 + tid;
    int d = i2 >> 3, g = i2 & 7;
    int gp = g ^ ((d >> 2) & 7);
    *(uint4*)(vt + ((size_t)(bh*64 + d)*T_ + t0 + g*8)) = *(const uint4*)&TT[d*64 + gp*8];
  }
}

// ---------------- flash attention v3 (verified r2): swapped-QK 32x32x16,
// in-register softmax, LDS-staged K/V with dbuf + stage-ahead ----------------
__launch_bounds__(128, 2)
__global__ void k_attn(const unsigned short* __restrict__ q,
                       const unsigned short* __restrict__ k,
                       const unsigned short* __restrict__ vt,
                       unsigned short* __restrict__ out){     // (B,T,D) bf16
  __shared__ __align__(16) unsigned short Kl[2][64*64];   // [row=k-pos][64 elems], chunks swizzled
  __shared__ __align__(16) unsigned short Vl[2][64*64];   // [row=d]    [64 t],     chunks swizzled
  const int tid  = threadIdx.x;
  const int wave = tid >> 6;      // 0..1
  const int lane = tid & 63;
  const int ln   = lane & 31;
  const int hi   = lane >> 5;
  const int id = blockIdx.x;
  const int bh = id & 31;                        // id%8==bh%8 -> head-local XCD
  const int q0 = (id >> 5)*64 + wave*32;         // this wave's 32 q-rows

  bf16x8 qf[4];
  {
    const unsigned short* qp = q + ((size_t)bh*T_ + q0 + ln)*HD_ + hi*8;
    #pragma unroll
    for (int kk = 0; kk < 4; kk++)
      qf[kk] = *(const bf16x8*)(qp + kk*16);
  }
  const unsigned short* kg = k  + (size_t)bh*T_*HD_;
  const unsigned short* vg = vt + (size_t)bh*HD_*T_;

  auto stage = [&](int buf, int kt){
    #pragma unroll
    for (int rr = 0; rr < 4; rr++){
      int idx = rr*128 + tid;
      int row = idx >> 3, c = idx & 7;
      int g = c ^ (row & 7);
      gl_lds16(kg + (size_t)(kt + row)*HD_ + g*8, &Kl[buf][(idx & ~63)*8]);
      gl_lds16(vg + (size_t)row*T_ + kt + g*8,    &Vl[buf][(idx & ~63)*8]);
    }
  };

  f32x16 o0 = {}, o1 = {};
  float ls[4] = {};
  const int vr0 = ln*64, vr1 = (32 + ln)*64;
  const int sw = ln & 7;

  stage(0, 0);
  __syncthreads();

  for (int t = 0; t < T_/64; t++){
    const int cur = t & 1, nxt = cur ^ 1;
    if (t + 1 < T_/64) stage(nxt, (t + 1)*64);
    const unsigned short* Kc = Kl[cur];
    const unsigned short* Vc = Vl[cur];
    #pragma unroll
    for (int s2 = 0; s2 < 2; s2++){
      bf16x8 kf[4];
      const int kb = (s2*32 + ln)*64;
      #pragma unroll
      for (int kk = 0; kk < 4; kk++){
        int ch = (kk*2 + hi) ^ sw;
        kf[kk] = *(const bf16x8*)&Kc[kb + ch*8];
      }
      f32x16 sa = {}, sb = {};
      __builtin_amdgcn_s_setprio(1);
      sa = __builtin_amdgcn_mfma_f32_32x32x16_bf16(kf[0], qf[0], sa, 0, 0, 0);
      sb = __builtin_amdgcn_mfma_f32_32x32x16_bf16(kf[1], qf[1], sb, 0, 0, 0);
      sa = __builtin_amdgcn_mfma_f32_32x32x16_bf16(kf[2], qf[2], sa, 0, 0, 0);
      sb = __builtin_amdgcn_mfma_f32_32x32x16_bf16(kf[3], qf[3], sb, 0, 0, 0);
      __builtin_amdgcn_s_setprio(0);
      union { uint2 u2[2]; bf16x8 v; } v0f[2], v1f[2];
      #pragma unroll
      for (int c = 0; c < 2; c++){
        int chA = (s2*4 + c*2)     ^ sw;
        int chB = (s2*4 + c*2 + 1) ^ sw;
        v0f[c].u2[0] = *(const uint2*)&Vc[vr0 + chA*8 + hi*4];
        v0f[c].u2[1] = *(const uint2*)&Vc[vr0 + chB*8 + hi*4];
        v1f[c].u2[0] = *(const uint2*)&Vc[vr1 + chA*8 + hi*4];
        v1f[c].u2[1] = *(const uint2*)&Vc[vr1 + chB*8 + hi*4];
      }
      f32x16 sv = sa + sb;
      float p[16];
      #pragma unroll
      for (int r = 0; r < 16; r++)
        p[r] = __expf(fminf(sv[r]*0.125f, 30.f));
      union { __bf16 h[16]; bf16x8 v[2]; } pa;
      #pragma unroll
      for (int r = 0; r < 16; r++){
        pa.h[r] = (__bf16)p[r];
        ls[r & 3] += p[r];
      }
      __builtin_amdgcn_s_setprio(1);
      o0 = __builtin_amdgcn_mfma_f32_32x32x16_bf16(pa.v[0], v0f[0].v, o0, 0, 0, 0);
      o1 = __builtin_amdgcn_mfma_f32_32x32x16_bf16(pa.v[0], v1f[0].v, o1, 0, 0, 0);
      o0 = __builtin_amdgcn_mfma_f32_32x32x16_bf16(pa.v[1], v0f[1].v, o0, 0, 0, 0);
      o1 = __builtin_amdgcn_mfma_f32_32x32x16_bf16(pa.v[1], v1f[1].v, o1, 0, 0, 0);
      __builtin_amdgcn_s_setprio(0);
    }
    __syncthreads();
  }

  float lsum = ls[0] + ls[1] + ls[2] + ls[3];
  lsum += __shfl_xor(lsum, 32, 64);
  float inv = 1.f / lsum;
  const int b = bh >> 4, h = bh & 15;
  unsigned short* ob = out + ((size_t)(b*T_ + q0))*D_ + h*64 + ln;
  #pragma unroll
  for (int r = 0; r < 16; r++){
    int qr = (r & 3) + 8*(r >> 2) + 4*hi;
    float invr = __shfl(inv, qr, 64);
    unsigned short* op = ob + (size_t)qr*D_;
    op[0]  = f2bf(o0[r]*invr);
    op[32] = f2bf(o1[r]*invr);
  }
}

extern "C" void kernel_launch(void* const* d_in, const int* in_sizes, int n_in,
                              void* d_out, int out_size, void* d_ws, size_t ws_size,
                              hipStream_t stream){
  const float* x      = (const float*)d_in[0];
  const float* cond   = (const float*)d_in[1];
  const float* norm1w = (const float*)d_in[2];
  const float* qkv_w  = (const float*)d_in[3];
  const float* q_nw   = (const float*)d_in[4];
  const float* k_nw   = (const float*)d_in[5];
  const float* proj_w = (const float*)d_in[6];
  const float* proj_b = (const float*)d_in[7];
  const float* norm2w = (const float*)d_in[8];
  const float* fc1_w  = (const float*)d_in[9];
  const float* fc1_b  = (const float*)d_in[10];
  const float* fc2_w  = (const float*)d_in[11];
  const float* fc2_b  = (const float*)d_in[12];
  const float* ada_w  = (const float*)d_in[13];
  const float* ada_b  = (const float*)d_in[14];
  const int*   wptr   = (const int*)d_in[16];
  float* out = (float*)d_out;

  char* ws = (char*)d_ws;
  size_t off = 0;
  auto alloc = [&](size_t bytes)->void*{
    void* p = ws + off; off += (bytes + 255) & ~(size_t)255; return p;
  };
  unsigned short* w_qkv  = (unsigned short*)alloc(3072ull*1024*2);
  unsigned short* w_proj = (unsigned short*)alloc(1024ull*1024*2);
  unsigned short* w_fc1  = (unsigned short*)alloc(8192ull*1024*2);
  unsigned short* w_fc2  = (unsigned short*)alloc(1024ull*4096*2);
  float* ada             = (float*)alloc((size_t)B_*SIX_D*4);
  unsigned short* h1     = (unsigned short*)alloc(4096ull*1024*2);
  // region R: qkv_out bf16 (25 MB) lives until k_vtrans; afterwards reused
  char* R                = (char*)alloc(4096ull*3072*4);
  unsigned short* qkv_out= (unsigned short*)R;
  unsigned short* attn_o = (unsigned short*)R;                       // 8.39 MB (after qkv dead)
  float* x1              = (float*)(R + (size_t)B_*T_*D_*2);         // 16.78 MB
  unsigned short* qb     = (unsigned short*)alloc(32ull*2048*64*2);
  unsigned short* kb     = (unsigned short*)alloc(32ull*2048*64*2);
  unsigned short* vt     = (unsigned short*)alloc(32ull*64*2048*2);
  unsigned short* mlp    = (unsigned short*)alloc(4096ull*4096*2);
  (void)ws_size; (void)in_sizes; (void)n_in; (void)out_size;

  k_conv_all<<<16384, 256, 0, stream>>>(qkv_w, proj_w, fc1_w, fc2_w, w_qkv, w_proj, w_fc1, w_fc2);

  k_ada<<<dim3(SIX_D/64, B_), 256, 0, stream>>>(cond, ada_w, ada_b, ada);
  k_norm_mod<<<B_*T_, 256, 0, stream>>>(x, norm1w, ada, 0, D_, h1);
  k_gemm_bt<EPI_BF16><<<dim3(3072/128, 4096/128), 256, 0, stream>>>(
      h1, w_qkv, B_*T_, 3*D_, D_, qkv_out, nullptr, nullptr, 0, nullptr);
  k_qkv_post<<<B_*T_*NH_/4, 256, 0, stream>>>(qkv_out, q_nw, k_nw, wptr, qb, kb);
  k_vtrans<<<dim3(T_/64, 32), 256, 0, stream>>>(qkv_out, vt);
  k_attn<<<1024, 128, 0, stream>>>(qb, kb, vt, attn_o);
  k_gemm_bt64<EPI_RESID><<<dim3(1024/128, 4096/64), 256, 0, stream>>>(
      attn_o, w_proj, B_*T_, D_, D_, x1, x, ada, 2*D_, proj_b);
  k_norm_mod<<<B_*T_, 256, 0, stream>>>(x1, norm2w, ada, 3*D_, 4*D_, h1);
  k_gemm_fc1<<<dim3(HID_/64, 4096/128), 256, 0, stream>>>(h1, w_fc1, fc1_b, mlp);
  k_gemm_bt64<EPI_RESID><<<dim3(1024/128, 4096/64), 256, 0, stream>>>(
      mlp, w_fc2, B_*T_, D_, HID_, out, x1, ada, 5*D_, fc2_b);
}